// Round 1
// baseline (834.436 us; speedup 1.0000x reference)
//
#include <hip/hip_runtime.h>

#define N_NODESC 50000
#define N_EDGESC 800000
#define NFEATC 128
#define NHIDC 64
#define NHEADC 4
#define NBASEC 8
#define NCLASSC 40
#define HD1C (NHEADC * NHIDC)        // 256
#define W1COLSC (HD1C + NBASEC)      // 264
#define W2COLSC (NCLASSC + NBASEC)   // 48

// ---------------- generic fp32 tiled GEMM: C[MxN] = A[MxK] @ B[KxN] ----------------
// 64x64 tile, 256 threads, 4x4 per thread, TK=16. K must be a multiple of 16.
__global__ __launch_bounds__(256) void gemm64(const float* __restrict__ A,
                                              const float* __restrict__ B,
                                              float* __restrict__ C,
                                              int M, int N, int K) {
  __shared__ float As[16][68];  // [k][m], +4 pad keeps 16B alignment, kills conflicts
  __shared__ float Bs[16][68];  // [k][n]
  const int tid = threadIdx.x;
  const int tx = tid & 15;
  const int ty = tid >> 4;
  const int row0 = blockIdx.x * 64;
  const int col0 = blockIdx.y * 64;
  float acc[4][4] = {{0.f}};

  for (int k0 = 0; k0 < K; k0 += 16) {
    // A tile: 64 rows x 16 k. thread -> (kk = tid&15, r = tid>>4), 4 passes of 16 rows
    {
      const int kk = tid & 15;
      const int r = tid >> 4;
#pragma unroll
      for (int p = 0; p < 4; ++p) {
        const int row = row0 + r + p * 16;
        float v = 0.f;
        if (row < M) v = A[(size_t)row * K + k0 + kk];
        As[kk][r + p * 16] = v;
      }
    }
    // B tile: 16 k x 64 cols. thread -> (col = tid&63, kk0 = tid>>6), 4 passes
    {
      const int c = tid & 63;
      const int kk0 = tid >> 6;
#pragma unroll
      for (int p = 0; p < 4; ++p) {
        const int kk = kk0 + p * 4;
        const int col = col0 + c;
        float v = 0.f;
        if (col < N) v = B[(size_t)(k0 + kk) * N + col];
        Bs[kk][c] = v;
      }
    }
    __syncthreads();
#pragma unroll
    for (int kk = 0; kk < 16; ++kk) {
      const float4 av = *reinterpret_cast<const float4*>(&As[kk][ty * 4]);
      const float4 bv = *reinterpret_cast<const float4*>(&Bs[kk][tx * 4]);
      acc[0][0] += av.x * bv.x; acc[0][1] += av.x * bv.y; acc[0][2] += av.x * bv.z; acc[0][3] += av.x * bv.w;
      acc[1][0] += av.y * bv.x; acc[1][1] += av.y * bv.y; acc[1][2] += av.y * bv.z; acc[1][3] += av.y * bv.w;
      acc[2][0] += av.z * bv.x; acc[2][1] += av.z * bv.y; acc[2][2] += av.z * bv.z; acc[2][3] += av.z * bv.w;
      acc[3][0] += av.w * bv.x; acc[3][1] += av.w * bv.y; acc[3][2] += av.w * bv.z; acc[3][3] += av.w * bv.w;
    }
    __syncthreads();
  }
#pragma unroll
  for (int i = 0; i < 4; ++i) {
    const int row = row0 + ty * 4 + i;
    if (row >= M) continue;
#pragma unroll
    for (int j = 0; j < 4; ++j) {
      const int col = col0 + tx * 4 + j;
      if (col < N) C[(size_t)row * N + col] = acc[i][j];
    }
  }
}

// ---------------- concat [W | B] columns into one weight matrix ----------------
__global__ void concat_cols(const float* __restrict__ Wm, int wcols,
                            const float* __restrict__ Bm, int bcols,
                            float* __restrict__ out, int rows) {
  const int tot = rows * (wcols + bcols);
  const int stride = gridDim.x * blockDim.x;
  for (int i = blockIdx.x * blockDim.x + threadIdx.x; i < tot; i += stride) {
    const int r = i / (wcols + bcols);
    const int c = i - r * (wcols + bcols);
    out[i] = (c < wcols) ? Wm[(size_t)r * wcols + c] : Bm[(size_t)r * bcols + (c - wcols)];
  }
}

// ---------------- per-node attention scalars ----------------
__global__ void attn_scalars1(const float* __restrict__ h1ext,
                              const float* __restrict__ cs1, const float* __restrict__ cd1,
                              float* __restrict__ esrc, float* __restrict__ edst) {
  const int n = blockIdx.x * blockDim.x + threadIdx.x;
  if (n >= N_NODESC) return;
  const float* s = h1ext + (size_t)n * W1COLSC + HD1C;
  float sb[NBASEC];
#pragma unroll
  for (int b = 0; b < NBASEC; ++b) sb[b] = s[b];
#pragma unroll
  for (int h = 0; h < NHEADC; ++h) {
    float a = 0.f, d = 0.f;
#pragma unroll
    for (int b = 0; b < NBASEC; ++b) {
      a += sb[b] * cs1[b * NHEADC + h];
      d += sb[b] * cd1[b * NHEADC + h];
    }
    esrc[n * NHEADC + h] = a;
    edst[n * NHEADC + h] = d;
  }
}

__global__ void attn_scalars2(const float* __restrict__ g2ext,
                              const float* __restrict__ cs2, const float* __restrict__ cd2,
                              float* __restrict__ esrc, float* __restrict__ edst) {
  const int n = blockIdx.x * blockDim.x + threadIdx.x;
  if (n >= N_NODESC) return;
  const float* s = g2ext + (size_t)n * W2COLSC + NCLASSC;
  float a = 0.f, d = 0.f;
#pragma unroll
  for (int b = 0; b < NBASEC; ++b) {
    a += s[b] * cs2[b];
    d += s[b] * cd2[b];
  }
  esrc[n] = a;
  edst[n] = d;
}

// ---------------- CSR build (by destination node) ----------------
__global__ void hist_kernel(const int* __restrict__ dst, int* __restrict__ counts) {
  const int stride = gridDim.x * blockDim.x;
  for (int e = blockIdx.x * blockDim.x + threadIdx.x; e < N_EDGESC; e += stride)
    atomicAdd(&counts[dst[e]], 1);
}

__global__ void scan_kernel(const int* __restrict__ counts, int* __restrict__ offsets, int n) {
  __shared__ int tmp[1024];
  int carry = 0;
  for (int base = 0; base < n; base += 1024) {
    const int i = base + (int)threadIdx.x;
    const int v = (i < n) ? counts[i] : 0;
    tmp[threadIdx.x] = v;
    __syncthreads();
    for (int d = 1; d < 1024; d <<= 1) {
      const int t = (threadIdx.x >= (unsigned)d) ? tmp[threadIdx.x - d] : 0;
      __syncthreads();
      tmp[threadIdx.x] += t;
      __syncthreads();
    }
    if (i < n) offsets[i] = carry + tmp[threadIdx.x] - v;  // exclusive
    carry += tmp[1023];
    __syncthreads();
  }
  if (threadIdx.x == 0) offsets[n] = carry;
}

__global__ void scatter_kernel(const int* __restrict__ dst, const int* __restrict__ offsets,
                               int* __restrict__ counts, int* __restrict__ eids) {
  const int stride = gridDim.x * blockDim.x;
  for (int e = blockIdx.x * blockDim.x + threadIdx.x; e < N_EDGESC; e += stride) {
    const int n = dst[e];
    const int pos = offsets[n] + atomicSub(&counts[n], 1) - 1;
    eids[pos] = e;
  }
}

// ---------------- layer-1 softmax-aggregate + bias + ELU ----------------
// one wave (64 lanes) per node; lane covers 4 consecutive features (float4),
// head = lane/16. Softmax denominator recomputed per-lane (uniform within a head).
__global__ __launch_bounds__(256) void agg1_kernel(
    const float* __restrict__ h1ext, const float* __restrict__ esrc,
    const float* __restrict__ edst, const int* __restrict__ srcArr,
    const int* __restrict__ offsets, const int* __restrict__ eids,
    const float* __restrict__ bias, float* __restrict__ hact) {
  const int wv = threadIdx.x >> 6;
  const int lane = threadIdx.x & 63;
  const int n = blockIdx.x * 4 + wv;
  if (n >= N_NODESC) return;
  const int h = lane >> 4;
  const int f = lane << 2;
  const int beg = offsets[n], end = offsets[n + 1];
  const float ed = edst[n * NHEADC + h];

  float wsum = 0.f;
  for (int i = beg; i < end; ++i) {
    const int s = srcArr[eids[i]];
    float t = esrc[s * NHEADC + h] + ed;
    t = t > 0.f ? t : 0.2f * t;
    wsum += __expf(t);
  }
  const float inv = 1.f / (wsum + 1e-16f);

  float ax = 0.f, ay = 0.f, az = 0.f, aw = 0.f;
  for (int i = beg; i < end; ++i) {
    const int e = eids[i];
    const int s = srcArr[e];
    float t = esrc[s * NHEADC + h] + ed;
    t = t > 0.f ? t : 0.2f * t;
    const float a = __expf(t) * inv;
    const float4 hv = *reinterpret_cast<const float4*>(h1ext + (size_t)s * W1COLSC + f);
    ax += a * hv.x; ay += a * hv.y; az += a * hv.z; aw += a * hv.w;
  }
  const float4 bb = *reinterpret_cast<const float4*>(bias + f);
  float4 o;
  o.x = ax + bb.x; o.x = o.x > 0.f ? o.x : __expf(o.x) - 1.f;
  o.y = ay + bb.y; o.y = o.y > 0.f ? o.y : __expf(o.y) - 1.f;
  o.z = az + bb.z; o.z = o.z > 0.f ? o.z : __expf(o.z) - 1.f;
  o.w = aw + bb.w; o.w = o.w > 0.f ? o.w : __expf(o.w) - 1.f;
  *reinterpret_cast<float4*>(hact + (size_t)n * HD1C + f) = o;
}

// ---------------- layer-2 softmax-aggregate (1 head, 40 classes) ----------------
__global__ __launch_bounds__(256) void agg2_kernel(
    const float* __restrict__ g2ext, const float* __restrict__ esrc,
    const float* __restrict__ edst, const int* __restrict__ srcArr,
    const int* __restrict__ offsets, const int* __restrict__ eids,
    float* __restrict__ out) {
  const int wv = threadIdx.x >> 6;
  const int lane = threadIdx.x & 63;
  const int n = blockIdx.x * 4 + wv;
  if (n >= N_NODESC) return;
  const int beg = offsets[n], end = offsets[n + 1];
  const float ed = edst[n];

  float wsum = 0.f;
  for (int i = beg; i < end; ++i) {
    const int s = srcArr[eids[i]];
    float t = esrc[s] + ed;
    t = t > 0.f ? t : 0.2f * t;
    wsum += __expf(t);
  }
  const float inv = 1.f / (wsum + 1e-16f);

  float acc = 0.f;
  for (int i = beg; i < end; ++i) {
    const int s = srcArr[eids[i]];
    float t = esrc[s] + ed;
    t = t > 0.f ? t : 0.2f * t;
    const float a = __expf(t) * inv;
    if (lane < NCLASSC) acc += a * g2ext[(size_t)s * W2COLSC + lane];
  }
  if (lane < NCLASSC) out[(size_t)n * NCLASSC + lane] = acc;
}

extern "C" void kernel_launch(void* const* d_in, const int* in_sizes, int n_in,
                              void* d_out, int out_size, void* d_ws, size_t ws_size,
                              hipStream_t stream) {
  const float* x   = (const float*)d_in[0];
  const int*   ei  = (const int*)d_in[1];
  const float* W1  = (const float*)d_in[2];
  const float* b1  = (const float*)d_in[3];
  const float* B1  = (const float*)d_in[4];
  const float* cs1 = (const float*)d_in[5];
  const float* cd1 = (const float*)d_in[6];
  const float* W2  = (const float*)d_in[7];
  const float* B2  = (const float*)d_in[8];
  const float* cs2 = (const float*)d_in[9];
  const float* cd2 = (const float*)d_in[10];
  const int* srcA = ei;
  const int* dstA = ei + N_EDGESC;
  float* out = (float*)d_out;

  char* ws = (char*)d_ws;
  size_t off = 0;
  auto alloc = [&](size_t bytes) -> void* {
    void* p = ws + off;
    off += (bytes + 255) & ~(size_t)255;
    return p;
  };
  float* h1ext  = (float*)alloc((size_t)N_NODESC * W1COLSC * 4);  // [N,264] = h1 | s1
  float* hact   = (float*)alloc((size_t)N_NODESC * HD1C * 4);     // elu(agg1) [N,256]
  float* g2ext  = (float*)alloc((size_t)N_NODESC * W2COLSC * 4);  // [N,48] = h2 | s2
  float* esrc1  = (float*)alloc((size_t)N_NODESC * NHEADC * 4);
  float* edst1  = (float*)alloc((size_t)N_NODESC * NHEADC * 4);
  float* esrc2  = (float*)alloc((size_t)N_NODESC * 4);
  float* edst2  = (float*)alloc((size_t)N_NODESC * 4);
  float* WB1    = (float*)alloc((size_t)NFEATC * W1COLSC * 4);
  float* WB2    = (float*)alloc((size_t)HD1C * W2COLSC * 4);
  int* counts   = (int*)alloc((size_t)N_NODESC * 4);
  int* offsets  = (int*)alloc((size_t)(N_NODESC + 1) * 4);
  int* eids     = (int*)alloc((size_t)N_EDGESC * 4);

  hipMemsetAsync(counts, 0, (size_t)N_NODESC * 4, stream);

  concat_cols<<<256, 256, 0, stream>>>(W1, HD1C, B1, NBASEC, WB1, NFEATC);
  concat_cols<<<256, 256, 0, stream>>>(W2, NCLASSC, B2, NBASEC, WB2, HD1C);

  hist_kernel<<<2048, 256, 0, stream>>>(dstA, counts);
  scan_kernel<<<1, 1024, 0, stream>>>(counts, offsets, N_NODESC);
  scatter_kernel<<<2048, 256, 0, stream>>>(dstA, offsets, counts, eids);

  dim3 g1((N_NODESC + 63) / 64, (W1COLSC + 63) / 64);
  gemm64<<<g1, 256, 0, stream>>>(x, WB1, h1ext, N_NODESC, W1COLSC, NFEATC);
  attn_scalars1<<<(N_NODESC + 255) / 256, 256, 0, stream>>>(h1ext, cs1, cd1, esrc1, edst1);
  agg1_kernel<<<(N_NODESC + 3) / 4, 256, 0, stream>>>(h1ext, esrc1, edst1, srcA, offsets,
                                                      eids, b1, hact);

  dim3 g2((N_NODESC + 63) / 64, (W2COLSC + 63) / 64);
  gemm64<<<g2, 256, 0, stream>>>(hact, WB2, g2ext, N_NODESC, W2COLSC, HD1C);
  attn_scalars2<<<(N_NODESC + 255) / 256, 256, 0, stream>>>(g2ext, cs2, cd2, esrc2, edst2);
  agg2_kernel<<<(N_NODESC + 3) / 4, 256, 0, stream>>>(g2ext, esrc2, edst2, srcA, offsets,
                                                      eids, out);
}

// Round 2
// 465.520 us; speedup vs baseline: 1.7925x; 1.7925x over previous
//
#include <hip/hip_runtime.h>

#define N_NODESC 50000
#define N_EDGESC 800000
#define NFEATC 128
#define NHIDC 64
#define NHEADC 4
#define NBASEC 8
#define NCLASSC 40
#define HD1C (NHEADC * NHIDC)        // 256
#define W1COLSC (HD1C + NBASEC)      // 264
#define W2COLSC (NCLASSC + NBASEC)   // 48

// ---------------- generic fp32 tiled GEMM: C[MxN] = A[MxK] @ B[KxN] ----------------
__global__ __launch_bounds__(256) void gemm64(const float* __restrict__ A,
                                              const float* __restrict__ B,
                                              float* __restrict__ C,
                                              int M, int N, int K) {
  __shared__ float As[16][68];
  __shared__ float Bs[16][68];
  const int tid = threadIdx.x;
  const int tx = tid & 15;
  const int ty = tid >> 4;
  const int row0 = blockIdx.x * 64;
  const int col0 = blockIdx.y * 64;
  float acc[4][4] = {{0.f}};

  for (int k0 = 0; k0 < K; k0 += 16) {
    {
      const int kk = tid & 15;
      const int r = tid >> 4;
#pragma unroll
      for (int p = 0; p < 4; ++p) {
        const int row = row0 + r + p * 16;
        float v = 0.f;
        if (row < M) v = A[(size_t)row * K + k0 + kk];
        As[kk][r + p * 16] = v;
      }
    }
    {
      const int c = tid & 63;
      const int kk0 = tid >> 6;
#pragma unroll
      for (int p = 0; p < 4; ++p) {
        const int kk = kk0 + p * 4;
        const int col = col0 + c;
        float v = 0.f;
        if (col < N) v = B[(size_t)(k0 + kk) * N + col];
        Bs[kk][c] = v;
      }
    }
    __syncthreads();
#pragma unroll
    for (int kk = 0; kk < 16; ++kk) {
      const float4 av = *reinterpret_cast<const float4*>(&As[kk][ty * 4]);
      const float4 bv = *reinterpret_cast<const float4*>(&Bs[kk][tx * 4]);
      acc[0][0] += av.x * bv.x; acc[0][1] += av.x * bv.y; acc[0][2] += av.x * bv.z; acc[0][3] += av.x * bv.w;
      acc[1][0] += av.y * bv.x; acc[1][1] += av.y * bv.y; acc[1][2] += av.y * bv.z; acc[1][3] += av.y * bv.w;
      acc[2][0] += av.z * bv.x; acc[2][1] += av.z * bv.y; acc[2][2] += av.z * bv.z; acc[2][3] += av.z * bv.w;
      acc[3][0] += av.w * bv.x; acc[3][1] += av.w * bv.y; acc[3][2] += av.w * bv.z; acc[3][3] += av.w * bv.w;
    }
    __syncthreads();
  }
#pragma unroll
  for (int i = 0; i < 4; ++i) {
    const int row = row0 + ty * 4 + i;
    if (row >= M) continue;
#pragma unroll
    for (int j = 0; j < 4; ++j) {
      const int col = col0 + tx * 4 + j;
      if (col < N) C[(size_t)row * N + col] = acc[i][j];
    }
  }
}

// ---------------- concat [W | B] columns ----------------
__global__ void concat_cols(const float* __restrict__ Wm, int wcols,
                            const float* __restrict__ Bm, int bcols,
                            float* __restrict__ out, int rows) {
  const int tot = rows * (wcols + bcols);
  const int stride = gridDim.x * blockDim.x;
  for (int i = blockIdx.x * blockDim.x + threadIdx.x; i < tot; i += stride) {
    const int r = i / (wcols + bcols);
    const int c = i - r * (wcols + bcols);
    out[i] = (c < wcols) ? Wm[(size_t)r * wcols + c] : Bm[(size_t)r * bcols + (c - wcols)];
  }
}

// ---------------- per-node attention scalars ----------------
__global__ void attn_scalars1(const float* __restrict__ h1ext,
                              const float* __restrict__ cs1, const float* __restrict__ cd1,
                              float* __restrict__ esrc, float* __restrict__ edst) {
  const int n = blockIdx.x * blockDim.x + threadIdx.x;
  if (n >= N_NODESC) return;
  const float* s = h1ext + (size_t)n * W1COLSC + HD1C;
  float sb[NBASEC];
#pragma unroll
  for (int b = 0; b < NBASEC; ++b) sb[b] = s[b];
#pragma unroll
  for (int h = 0; h < NHEADC; ++h) {
    float a = 0.f, d = 0.f;
#pragma unroll
    for (int b = 0; b < NBASEC; ++b) {
      a += sb[b] * cs1[b * NHEADC + h];
      d += sb[b] * cd1[b * NHEADC + h];
    }
    esrc[n * NHEADC + h] = a;
    edst[n * NHEADC + h] = d;
  }
}

__global__ void attn_scalars2(const float* __restrict__ g2ext,
                              const float* __restrict__ cs2, const float* __restrict__ cd2,
                              float* __restrict__ esrc, float* __restrict__ edst) {
  const int n = blockIdx.x * blockDim.x + threadIdx.x;
  if (n >= N_NODESC) return;
  const float* s = g2ext + (size_t)n * W2COLSC + NCLASSC;
  float a = 0.f, d = 0.f;
#pragma unroll
  for (int b = 0; b < NBASEC; ++b) {
    a += s[b] * cs2[b];
    d += s[b] * cd2[b];
  }
  esrc[n] = a;
  edst[n] = d;
}

// ---------------- CSR build (by destination node) ----------------
__global__ void hist_kernel(const int* __restrict__ dst, int* __restrict__ counts) {
  const int e = blockIdx.x * blockDim.x + threadIdx.x;
  if (e < N_EDGESC) atomicAdd(&counts[dst[e]], 1);
}

#define SCAN_NB ((N_NODESC + 255) / 256)   // 196

__global__ void reduce_counts(const int* __restrict__ counts, int* __restrict__ bsums) {
  __shared__ int sm[256];
  const int i = blockIdx.x * 256 + threadIdx.x;
  sm[threadIdx.x] = (i < N_NODESC) ? counts[i] : 0;
  __syncthreads();
  for (int d = 128; d > 0; d >>= 1) {
    if (threadIdx.x < (unsigned)d) sm[threadIdx.x] += sm[threadIdx.x + d];
    __syncthreads();
  }
  if (threadIdx.x == 0) bsums[blockIdx.x] = sm[0];
}

__global__ void scan_bsums_k(int* __restrict__ bsums) {
  __shared__ int sm[256];
  const int v = (threadIdx.x < SCAN_NB) ? bsums[threadIdx.x] : 0;
  sm[threadIdx.x] = v;
  __syncthreads();
  for (int d = 1; d < 256; d <<= 1) {
    const int t = (threadIdx.x >= (unsigned)d) ? sm[threadIdx.x - d] : 0;
    __syncthreads();
    sm[threadIdx.x] += t;
    __syncthreads();
  }
  if (threadIdx.x < SCAN_NB) bsums[threadIdx.x] = sm[threadIdx.x] - v;  // exclusive
}

__global__ void scan_final(const int* __restrict__ counts, const int* __restrict__ bsums,
                           int* __restrict__ offsets) {
  __shared__ int sm[256];
  const int i = blockIdx.x * 256 + threadIdx.x;
  const int v = (i < N_NODESC) ? counts[i] : 0;
  sm[threadIdx.x] = v;
  __syncthreads();
  for (int d = 1; d < 256; d <<= 1) {
    const int t = (threadIdx.x >= (unsigned)d) ? sm[threadIdx.x - d] : 0;
    __syncthreads();
    sm[threadIdx.x] += t;
    __syncthreads();
  }
  if (i < N_NODESC) offsets[i] = bsums[blockIdx.x] + sm[threadIdx.x] - v;
  if (i == 0) offsets[N_NODESC] = N_EDGESC;
}

// scatter src node ids directly into CSR (dst-grouped) order
__global__ void scatter_kernel(const int* __restrict__ dst, const int* __restrict__ src,
                               const int* __restrict__ offsets, int* __restrict__ counts,
                               int* __restrict__ srcs_csr) {
  const int e = blockIdx.x * blockDim.x + threadIdx.x;
  if (e >= N_EDGESC) return;
  const int n = dst[e];
  const int pos = offsets[n] + atomicSub(&counts[n], 1) - 1;
  srcs_csr[pos] = src[e];
}

// ---------------- layer-1 single-pass softmax-aggregate + bias + ELU ----------------
// one wave per node; lane covers 4 consecutive features, head = lane/16.
// out = (sum_i exp(t_i) * h[src_i]) / (sum_i exp(t_i))  -- shift-free softmax
__global__ __launch_bounds__(256) void agg1_kernel(
    const float* __restrict__ h1ext, const float* __restrict__ esrc,
    const float* __restrict__ edst, const int* __restrict__ srcs,
    const int* __restrict__ offsets, const float* __restrict__ bias,
    float* __restrict__ hact) {
  const int wv = threadIdx.x >> 6;
  const int lane = threadIdx.x & 63;
  const int n = blockIdx.x * 4 + wv;
  if (n >= N_NODESC) return;
  const int h = lane >> 4;
  const int f = lane << 2;
  const int beg = offsets[n], end = offsets[n + 1];
  const float ed = edst[n * NHEADC + h];

  float wsum = 0.f;
  float ax = 0.f, ay = 0.f, az = 0.f, aw = 0.f;
  int i = beg;
  for (; i + 4 <= end; i += 4) {
    const int s0 = srcs[i], s1 = srcs[i + 1], s2 = srcs[i + 2], s3 = srcs[i + 3];
    float t0 = esrc[s0 * NHEADC + h] + ed;
    float t1 = esrc[s1 * NHEADC + h] + ed;
    float t2 = esrc[s2 * NHEADC + h] + ed;
    float t3 = esrc[s3 * NHEADC + h] + ed;
    const float4 h0 = *reinterpret_cast<const float4*>(h1ext + (size_t)s0 * W1COLSC + f);
    const float4 h1 = *reinterpret_cast<const float4*>(h1ext + (size_t)s1 * W1COLSC + f);
    const float4 h2 = *reinterpret_cast<const float4*>(h1ext + (size_t)s2 * W1COLSC + f);
    const float4 h3 = *reinterpret_cast<const float4*>(h1ext + (size_t)s3 * W1COLSC + f);
    t0 = t0 > 0.f ? t0 : 0.2f * t0;
    t1 = t1 > 0.f ? t1 : 0.2f * t1;
    t2 = t2 > 0.f ? t2 : 0.2f * t2;
    t3 = t3 > 0.f ? t3 : 0.2f * t3;
    const float a0 = __expf(t0), a1 = __expf(t1), a2 = __expf(t2), a3 = __expf(t3);
    wsum += (a0 + a1) + (a2 + a3);
    ax += a0 * h0.x + a1 * h1.x + a2 * h2.x + a3 * h3.x;
    ay += a0 * h0.y + a1 * h1.y + a2 * h2.y + a3 * h3.y;
    az += a0 * h0.z + a1 * h1.z + a2 * h2.z + a3 * h3.z;
    aw += a0 * h0.w + a1 * h1.w + a2 * h2.w + a3 * h3.w;
  }
  for (; i < end; ++i) {
    const int s = srcs[i];
    float t = esrc[s * NHEADC + h] + ed;
    t = t > 0.f ? t : 0.2f * t;
    const float a = __expf(t);
    const float4 hv = *reinterpret_cast<const float4*>(h1ext + (size_t)s * W1COLSC + f);
    wsum += a;
    ax += a * hv.x; ay += a * hv.y; az += a * hv.z; aw += a * hv.w;
  }
  const float inv = 1.f / (wsum + 1e-16f);
  const float4 bb = *reinterpret_cast<const float4*>(bias + f);
  float4 o;
  o.x = ax * inv + bb.x; o.x = o.x > 0.f ? o.x : __expf(o.x) - 1.f;
  o.y = ay * inv + bb.y; o.y = o.y > 0.f ? o.y : __expf(o.y) - 1.f;
  o.z = az * inv + bb.z; o.z = o.z > 0.f ? o.z : __expf(o.z) - 1.f;
  o.w = aw * inv + bb.w; o.w = o.w > 0.f ? o.w : __expf(o.w) - 1.f;
  *reinterpret_cast<float4*>(hact + (size_t)n * HD1C + f) = o;
}

// ---------------- layer-2 single-pass softmax-aggregate (1 head, 40 classes) ----------------
__global__ __launch_bounds__(256) void agg2_kernel(
    const float* __restrict__ g2ext, const float* __restrict__ esrc,
    const float* __restrict__ edst, const int* __restrict__ srcs,
    const int* __restrict__ offsets, float* __restrict__ out) {
  const int wv = threadIdx.x >> 6;
  const int lane = threadIdx.x & 63;
  const int n = blockIdx.x * 4 + wv;
  if (n >= N_NODESC) return;
  const int beg = offsets[n], end = offsets[n + 1];
  const float ed = edst[n];

  float wsum = 0.f, acc = 0.f;
  const bool act = lane < NCLASSC;
  int i = beg;
  for (; i + 4 <= end; i += 4) {
    const int s0 = srcs[i], s1 = srcs[i + 1], s2 = srcs[i + 2], s3 = srcs[i + 3];
    float t0 = esrc[s0] + ed, t1 = esrc[s1] + ed, t2 = esrc[s2] + ed, t3 = esrc[s3] + ed;
    float g0 = 0.f, g1 = 0.f, g2v = 0.f, g3 = 0.f;
    if (act) {
      g0 = g2ext[(size_t)s0 * W2COLSC + lane];
      g1 = g2ext[(size_t)s1 * W2COLSC + lane];
      g2v = g2ext[(size_t)s2 * W2COLSC + lane];
      g3 = g2ext[(size_t)s3 * W2COLSC + lane];
    }
    t0 = t0 > 0.f ? t0 : 0.2f * t0;
    t1 = t1 > 0.f ? t1 : 0.2f * t1;
    t2 = t2 > 0.f ? t2 : 0.2f * t2;
    t3 = t3 > 0.f ? t3 : 0.2f * t3;
    const float a0 = __expf(t0), a1 = __expf(t1), a2 = __expf(t2), a3 = __expf(t3);
    wsum += (a0 + a1) + (a2 + a3);
    acc += a0 * g0 + a1 * g1 + a2 * g2v + a3 * g3;
  }
  for (; i < end; ++i) {
    const int s = srcs[i];
    float t = esrc[s] + ed;
    t = t > 0.f ? t : 0.2f * t;
    const float a = __expf(t);
    wsum += a;
    if (act) acc += a * g2ext[(size_t)s * W2COLSC + lane];
  }
  const float inv = 1.f / (wsum + 1e-16f);
  if (act) out[(size_t)n * NCLASSC + lane] = acc * inv;
}

extern "C" void kernel_launch(void* const* d_in, const int* in_sizes, int n_in,
                              void* d_out, int out_size, void* d_ws, size_t ws_size,
                              hipStream_t stream) {
  const float* x   = (const float*)d_in[0];
  const int*   ei  = (const int*)d_in[1];
  const float* W1  = (const float*)d_in[2];
  const float* b1  = (const float*)d_in[3];
  const float* B1  = (const float*)d_in[4];
  const float* cs1 = (const float*)d_in[5];
  const float* cd1 = (const float*)d_in[6];
  const float* W2  = (const float*)d_in[7];
  const float* B2  = (const float*)d_in[8];
  const float* cs2 = (const float*)d_in[9];
  const float* cd2 = (const float*)d_in[10];
  const int* srcA = ei;
  const int* dstA = ei + N_EDGESC;
  float* out = (float*)d_out;

  char* ws = (char*)d_ws;
  size_t off = 0;
  auto alloc = [&](size_t bytes) -> void* {
    void* p = ws + off;
    off += (bytes + 255) & ~(size_t)255;
    return p;
  };
  float* h1ext  = (float*)alloc((size_t)N_NODESC * W1COLSC * 4);
  float* hact   = (float*)alloc((size_t)N_NODESC * HD1C * 4);
  float* g2ext  = (float*)alloc((size_t)N_NODESC * W2COLSC * 4);
  float* esrc1  = (float*)alloc((size_t)N_NODESC * NHEADC * 4);
  float* edst1  = (float*)alloc((size_t)N_NODESC * NHEADC * 4);
  float* esrc2  = (float*)alloc((size_t)N_NODESC * 4);
  float* edst2  = (float*)alloc((size_t)N_NODESC * 4);
  float* WB1    = (float*)alloc((size_t)NFEATC * W1COLSC * 4);
  float* WB2    = (float*)alloc((size_t)HD1C * W2COLSC * 4);
  int* counts   = (int*)alloc((size_t)N_NODESC * 4);
  int* offsets  = (int*)alloc((size_t)(N_NODESC + 1) * 4);
  int* bsums    = (int*)alloc((size_t)SCAN_NB * 4);
  int* srcs_csr = (int*)alloc((size_t)N_EDGESC * 4);

  hipMemsetAsync(counts, 0, (size_t)N_NODESC * 4, stream);

  concat_cols<<<256, 256, 0, stream>>>(W1, HD1C, B1, NBASEC, WB1, NFEATC);
  concat_cols<<<256, 256, 0, stream>>>(W2, NCLASSC, B2, NBASEC, WB2, HD1C);

  hist_kernel<<<(N_EDGESC + 255) / 256, 256, 0, stream>>>(dstA, counts);
  reduce_counts<<<SCAN_NB, 256, 0, stream>>>(counts, bsums);
  scan_bsums_k<<<1, 256, 0, stream>>>(bsums);
  scan_final<<<SCAN_NB, 256, 0, stream>>>(counts, bsums, offsets);
  scatter_kernel<<<(N_EDGESC + 255) / 256, 256, 0, stream>>>(dstA, srcA, offsets, counts,
                                                             srcs_csr);

  dim3 g1((N_NODESC + 63) / 64, (W1COLSC + 63) / 64);
  gemm64<<<g1, 256, 0, stream>>>(x, WB1, h1ext, N_NODESC, W1COLSC, NFEATC);
  attn_scalars1<<<(N_NODESC + 255) / 256, 256, 0, stream>>>(h1ext, cs1, cd1, esrc1, edst1);
  agg1_kernel<<<(N_NODESC + 3) / 4, 256, 0, stream>>>(h1ext, esrc1, edst1, srcs_csr, offsets,
                                                      b1, hact);

  dim3 g2((N_NODESC + 63) / 64, (W2COLSC + 63) / 64);
  gemm64<<<g2, 256, 0, stream>>>(hact, WB2, g2ext, N_NODESC, W2COLSC, HD1C);
  attn_scalars2<<<(N_NODESC + 255) / 256, 256, 0, stream>>>(g2ext, cs2, cd2, esrc2, edst2);
  agg2_kernel<<<(N_NODESC + 3) / 4, 256, 0, stream>>>(g2ext, esrc2, edst2, srcs_csr, offsets,
                                                      out);
}